// Round 11
// baseline (3131.152 us; speedup 1.0000x reference)
//
#include <hip/hip_runtime.h>

typedef unsigned short ushort_t;
typedef __attribute__((ext_vector_type(8))) short v8s;
typedef __attribute__((ext_vector_type(4))) float v4f;
typedef __attribute__((ext_vector_type(4))) unsigned int v4u;
typedef __attribute__((ext_vector_type(4))) unsigned short v4h;

#define DEV __device__ __forceinline__

#define BB 128
#define TT 256
#define DD 256
#define UU 256
#define NG 1024
#define TB 32768  // T*B

#define L2E  1.4426950408889634f
#define L2E2 2.8853901617779268f

DEV ushort_t f2bf(float f){
  unsigned u = __builtin_bit_cast(unsigned, f);
  u = u + 0x7FFFu + ((u>>16)&1u);
  return (ushort_t)(u>>16);
}
DEV float bf2f(ushort_t h){
  unsigned u = ((unsigned)h)<<16;
  return __builtin_bit_cast(float, u);
}
// write-through store (L3-visible, no cache maintenance)
DEV void store_short_wt(ushort_t* p, ushort_t v){
  asm volatile("global_store_short %0, %1, off sc0 sc1" :: "v"(p), "v"((unsigned)v) : "memory");
}

// ---- prep: x (B,T,D) fp32 -> xb (T,B,D) bf16 ----
__global__ void prep_x(const float* __restrict__ x, ushort_t* __restrict__ xb){
  int tid = blockIdx.x*256 + threadIdx.x;
  int idx = tid*4;
  if (idx >= BB*TT*DD) return;
  int d0 = idx & 255, t = (idx>>8)&255, b = idx>>16;
  const float* s = x + ((size_t)(b*256+t))*256 + d0;
  ushort_t* o = xb + ((size_t)(t*128+b))*256 + d0;
  v4f v = *(const v4f*)s;
  o[0]=f2bf(v[0]); o[1]=f2bf(v[1]); o[2]=f2bf(v[2]); o[3]=f2bf(v[3]);
}

// ---- prep: W (L,K=256,N=1024) fp32 -> wt [d][L][n][k] bf16, pre-scaled by log2e ----
__global__ void prep_w(const float* __restrict__ wf, const float* __restrict__ wb,
                       ushort_t* __restrict__ wt){
  int tid = blockIdx.x*256 + threadIdx.x;           // 1,048,576 total
  int n = tid & 1023, k = (tid>>10)&255, L = (tid>>18)&1, d = (tid>>19)&1;
  const float* src = (d ? wb : wf) + (size_t)L*262144 + (size_t)k*1024 + n;
  float sc = ((n>>8)==2) ? L2E2 : L2E;
  wt[(size_t)((d*2+L)*1024 + n)*256 + k] = f2bf(*src * sc);
}

// ---- prep: R (L,256,1024) fp32 -> rp packed in MFMA B-fragment order, pre-scaled ----
__global__ void prep_r(const float* __restrict__ rf, const float* __restrict__ rb,
                       ushort_t* __restrict__ rp){
  int tid = blockIdx.x*256 + threadIdx.x;           // 1,048,576 total
  int gcol = tid & 1023, k = (tid>>10)&255, L = (tid>>18)&1, d = (tid>>19)&1;
  const float* src = (d ? rb : rf) + (size_t)L*262144 + (size_t)k*1024 + gcol;
  float sc = ((gcol>>8)==2) ? L2E2 : L2E;
  int g = gcol>>8, rem = gcol&255, slot = rem>>4, lo = rem&15;
  int ks = k>>5, hi = (k>>3)&3, j = k&7;
  int l = hi*16+lo, frag = ks*4+g;
  rp[(size_t)((d*2+L)*16 + slot)*16384 + (size_t)frag*512 + l*8 + j] = f2bf(*src * sc);
}

// ---- projection GEMM: xz[d][t*128+b][gc] = A @ W^T + bias*sc (all pre-scaled) ----
__global__ __launch_bounds__(256) void proj_gemm(
    const ushort_t* __restrict__ A_fw, const ushort_t* __restrict__ A_bw,
    const ushort_t* __restrict__ wt, int layer,
    const float* __restrict__ bias_fw, const float* __restrict__ bias_bw,
    ushort_t* __restrict__ xz)
{
  int d = blockIdx.z;
  const ushort_t* A = d ? A_bw : A_fw;
  const ushort_t* W = wt + (size_t)(d*2+layer)*262144;
  const float* bias = (d ? bias_bw : bias_fw) + layer*1024;
  ushort_t* out = xz + (size_t)d*TB*NG;
  int m0 = blockIdx.x*128, n0 = blockIdx.y*128;
  __shared__ ushort_t As[128*32];
  __shared__ ushort_t Bs[128*32];
  int tid = threadIdx.x;
  int w = tid>>6, l = tid&63, lo = l&15, hi = l>>4;
  int wm = w>>1, wn = w&1;
  v4f acc[4][4];
  #pragma unroll
  for (int i=0;i<4;++i)
    #pragma unroll
    for (int j=0;j<4;++j) acc[i][j] = (v4f){0.f,0.f,0.f,0.f};
  for (int kt=0; kt<8; ++kt){
    __syncthreads();
    #pragma unroll
    for (int p=0;p<2;++p){
      int c = tid + p*256;
      int row = c>>2, c4 = c&3;
      *(v4u*)(As + (size_t)c*8) = *(const v4u*)(A + (size_t)(m0+row)*256 + kt*32 + c4*8);
      *(v4u*)(Bs + (size_t)c*8) = *(const v4u*)(W + (size_t)(n0+row)*256 + kt*32 + c4*8);
    }
    __syncthreads();
    v8s af[4], bfv[4];
    #pragma unroll
    for (int mt=0;mt<4;++mt) af[mt] = *(const v8s*)(As + (size_t)(wm*64+mt*16+lo)*32 + hi*8);
    #pragma unroll
    for (int nt=0;nt<4;++nt) bfv[nt] = *(const v8s*)(Bs + (size_t)(wn*64+nt*16+lo)*32 + hi*8);
    #pragma unroll
    for (int mt=0;mt<4;++mt)
      #pragma unroll
      for (int nt=0;nt<4;++nt)
        acc[mt][nt] = __builtin_amdgcn_mfma_f32_16x16x32_bf16(af[mt], bfv[nt], acc[mt][nt], 0,0,0);
  }
  #pragma unroll
  for (int nt=0;nt<4;++nt){
    int col = n0 + wn*64 + nt*16 + lo;
    float bv = bias[col] * (((col>>8)==2) ? L2E2 : L2E);
    #pragma unroll
    for (int mt=0;mt<4;++mt){
      int row0 = m0 + wm*64 + mt*16 + hi*4;
      #pragma unroll
      for (int r=0;r<4;++r)
        out[(size_t)(row0+r)*NG + col] = f2bf(acc[mt][nt][r] + bv);
    }
  }
}

// ---- persistent LSTM recurrence, DUAL-CHAIN (fw+bw in the same wave) ----
// 32 blocks x 256 thr (1 wave/SIMD -> 512-reg budget; both R-slices in regs).
// bg = bid&7 (batch rows bg*16..+16), cw = bid>>3. slot = cw*4+w, U0 = slot*16.
// Each wave alternates fw/bw chain segments; each chain's sync round-trip
// hides under the other chain's compute.
// Protocol per chain (unchanged from R10): WT h-stores -> vmcnt(0) -> relaxed flag;
// consumer: relaxed 16-slot poll + __all. Spin BOUNDED (wrong answer beats hang).
__global__ __launch_bounds__(256,1) void rec_lstm(
    const ushort_t* __restrict__ xz, const ushort_t* __restrict__ rp,
    ushort_t* __restrict__ hbase, unsigned* __restrict__ flags, int layer)
{
  int bid = blockIdx.x;
  int bg = bid & 7, cw = bid >> 3;
  int tid = threadIdx.x, w = tid>>6, l = tid&63, lo = l&15, hi = l>>4;
  int b0 = bg*16;
  int slot = cw*4 + w;
  int U0 = slot*16;
  const ushort_t* xzf = xz;
  const ushort_t* xzb = xz + (size_t)TB*NG;
  ushort_t* hf = hbase;
  ushort_t* hb_ = hbase + (size_t)TB*UU;
  unsigned* flgf = flags + (size_t)bg*4096;          // fw: 256 steps x 16 slots
  unsigned* flgb = flags + (size_t)(8+bg)*4096;      // bw

  v8s bfrf[8][4], bfrb[8][4];
  {
    const ushort_t* rpf = rp + (size_t)((0*2+layer)*16 + slot)*16384 + l*8;
    const ushort_t* rpb = rp + (size_t)((1*2+layer)*16 + slot)*16384 + l*8;
    #pragma unroll
    for (int f=0;f<32;++f){
      ((v8s*)bfrf)[f] = *(const v8s*)(rpf + (size_t)f*512);
      ((v8s*)bfrb)[f] = *(const v8s*)(rpb + (size_t)f*512);
    }
  }
  float cf[4] = {0.f,0.f,0.f,0.f};
  float cb[4] = {0.f,0.f,0.f,0.f};

  for (int s=0;s<256;++s){
    int tf = s, tb = 255-s;
    // prefetch xz for both chains (independent of h; issued before any spin)
    float xzvf[4][4], xzvb[4][4];
    #pragma unroll
    for (int gg=0;gg<4;++gg)
      #pragma unroll
      for (int r=0;r<4;++r){
        xzvf[gg][r] = bf2f(xzf[(size_t)(tf*128 + b0 + hi*4 + r)*NG + gg*256 + U0 + lo]);
        xzvb[gg][r] = bf2f(xzb[(size_t)(tb*128 + b0 + hi*4 + r)*NG + gg*256 + U0 + lo]);
      }
    // ================= fw half-step =================
    {
      v4f acc[4];
      #pragma unroll
      for (int gg=0;gg<4;++gg) acc[gg] = (v4f){0.f,0.f,0.f,0.f};
      if (s>0){
        unsigned v; int spin = 0;
        do {
          v = __hip_atomic_load(&flgf[(s-1)*16 + (l&15)], __ATOMIC_RELAXED, __HIP_MEMORY_SCOPE_AGENT);
          if (++spin > 5000) break;   // failsafe
        } while (!__all(v != 0u));
        asm volatile("" ::: "memory");
        v8s a[8];
        #pragma unroll
        for (int ks=0;ks<8;++ks)
          a[ks] = *(const v8s*)(hf + (size_t)((tf-1)*128 + b0 + lo)*UU + ks*32 + hi*8);
        #pragma unroll
        for (int ks=0;ks<8;++ks)
          #pragma unroll
          for (int gg=0;gg<4;++gg)
            acc[gg] = __builtin_amdgcn_mfma_f32_16x16x32_bf16(a[ks], bfrf[ks][gg], acc[gg], 0,0,0);
      }
      #pragma unroll
      for (int r=0;r<4;++r){
        float zi = acc[0][r] + xzvf[0][r];
        float zf = acc[1][r] + xzvf[1][r];
        float zg = acc[2][r] + xzvf[2][r];
        float zo = acc[3][r] + xzvf[3][r];
        float ig = __builtin_amdgcn_rcpf(1.f + __builtin_amdgcn_exp2f(-zi));
        float fg = __builtin_amdgcn_rcpf(1.f + __builtin_amdgcn_exp2f(-zf));
        float og = __builtin_amdgcn_rcpf(1.f + __builtin_amdgcn_exp2f(-zo));
        float gt = 1.f - 2.f*__builtin_amdgcn_rcpf(1.f + __builtin_amdgcn_exp2f(zg));
        float cc = fg*cf[r] + ig*gt;
        cf[r] = cc;
        float th = 1.f - 2.f*__builtin_amdgcn_rcpf(1.f + __builtin_amdgcn_exp2f(L2E2*cc));
        store_short_wt(hf + (size_t)(tf*128 + b0 + hi*4 + r)*UU + U0 + lo, f2bf(og*th));
      }
      asm volatile("s_waitcnt vmcnt(0)" ::: "memory");
      if (l == 0)
        __hip_atomic_store(&flgf[s*16 + slot], 1u, __ATOMIC_RELAXED, __HIP_MEMORY_SCOPE_AGENT);
    }
    // ================= bw half-step =================
    {
      v4f acc[4];
      #pragma unroll
      for (int gg=0;gg<4;++gg) acc[gg] = (v4f){0.f,0.f,0.f,0.f};
      if (s>0){
        unsigned v; int spin = 0;
        do {
          v = __hip_atomic_load(&flgb[(s-1)*16 + (l&15)], __ATOMIC_RELAXED, __HIP_MEMORY_SCOPE_AGENT);
          if (++spin > 5000) break;   // failsafe
        } while (!__all(v != 0u));
        asm volatile("" ::: "memory");
        v8s a[8];
        #pragma unroll
        for (int ks=0;ks<8;++ks)
          a[ks] = *(const v8s*)(hb_ + (size_t)((tb+1)*128 + b0 + lo)*UU + ks*32 + hi*8);
        #pragma unroll
        for (int ks=0;ks<8;++ks)
          #pragma unroll
          for (int gg=0;gg<4;++gg)
            acc[gg] = __builtin_amdgcn_mfma_f32_16x16x32_bf16(a[ks], bfrb[ks][gg], acc[gg], 0,0,0);
      }
      #pragma unroll
      for (int r=0;r<4;++r){
        float zi = acc[0][r] + xzvb[0][r];
        float zf = acc[1][r] + xzvb[1][r];
        float zg = acc[2][r] + xzvb[2][r];
        float zo = acc[3][r] + xzvb[3][r];
        float ig = __builtin_amdgcn_rcpf(1.f + __builtin_amdgcn_exp2f(-zi));
        float fg = __builtin_amdgcn_rcpf(1.f + __builtin_amdgcn_exp2f(-zf));
        float og = __builtin_amdgcn_rcpf(1.f + __builtin_amdgcn_exp2f(-zo));
        float gt = 1.f - 2.f*__builtin_amdgcn_rcpf(1.f + __builtin_amdgcn_exp2f(zg));
        float cc = fg*cb[r] + ig*gt;
        cb[r] = cc;
        float th = 1.f - 2.f*__builtin_amdgcn_rcpf(1.f + __builtin_amdgcn_exp2f(L2E2*cc));
        store_short_wt(hb_ + (size_t)(tb*128 + b0 + hi*4 + r)*UU + U0 + lo, f2bf(og*th));
      }
      asm volatile("s_waitcnt vmcnt(0)" ::: "memory");
      if (l == 0)
        __hip_atomic_store(&flgb[s*16 + slot], 1u, __ATOMIC_RELAXED, __HIP_MEMORY_SCOPE_AGENT);
    }
  }
}

// ---- final combine: out(B,T,U) fp32 = 0.5*(h1f + h0f + h1b + h0b) ----
__global__ void combine(const ushort_t* __restrict__ h, float* __restrict__ out){
  int tid = blockIdx.x*256 + threadIdx.x;
  int idx = tid*4;
  if (idx >= BB*TT*UU) return;
  int u = idx&255, t = (idx>>8)&255, b = idx>>16;
  size_t o = (size_t)(t*128+b)*256 + u;
  const size_t S = (size_t)TB*UU;
  v4h a0 = *(const v4h*)(h + 0*S + o);   // L0 fw
  v4h a1 = *(const v4h*)(h + 1*S + o);   // L0 bw
  v4h a2 = *(const v4h*)(h + 2*S + o);   // L1 fw
  v4h a3 = *(const v4h*)(h + 3*S + o);   // L1 bw
  v4f res;
  #pragma unroll
  for (int k=0;k<4;++k)
    res[k] = 0.5f*(bf2f(a0[k]) + bf2f(a1[k]) + bf2f(a2[k]) + bf2f(a3[k]));
  *(v4f*)(out + ((size_t)(b*256+t))*256 + u) = res;
}

extern "C" void kernel_launch(void* const* d_in, const int* in_sizes, int n_in,
                              void* d_out, int out_size, void* d_ws, size_t ws_size,
                              hipStream_t stream)
{
  const float* x  = (const float*)d_in[0];
  const float* wf = (const float*)d_in[1];
  const float* rf = (const float*)d_in[2];
  const float* bf = (const float*)d_in[3];
  const float* wb = (const float*)d_in[4];
  const float* rb = (const float*)d_in[5];
  const float* bb = (const float*)d_in[6];
  char* ws = (char*)d_ws;

  const size_t XB_OFF = 0;                                   // 16,777,216
  const size_t WT_OFF = XB_OFF + (size_t)TB*DD*2;
  const size_t RP_OFF = WT_OFF + (size_t)2*2*1024*256*2;     // +2,097,152
  const size_t XZ_OFF = RP_OFF + (size_t)2*2*256*1024*2;     // +2,097,152
  const size_t H_OFF  = XZ_OFF + (size_t)2*TB*NG*2;          // +134,217,728
  const size_t FL_OFF = H_OFF  + (size_t)4*TB*UU*2;          // +67,108,864

  ushort_t* xb = (ushort_t*)(ws + XB_OFF);
  ushort_t* wt = (ushort_t*)(ws + WT_OFF);
  ushort_t* rp = (ushort_t*)(ws + RP_OFF);
  ushort_t* xz = (ushort_t*)(ws + XZ_OFF);
  ushort_t* h  = (ushort_t*)(ws + H_OFF);
  unsigned* flags = (unsigned*)(ws + FL_OFF);
  const size_t S = (size_t)TB*UU;
  const size_t FL_PER_LAYER = 16*256*16;   // chains x steps x slots (uints)

  hipMemsetAsync(flags, 0, 2*FL_PER_LAYER*4, stream);
  prep_x<<<8192,256,0,stream>>>(x, xb);
  prep_w<<<4096,256,0,stream>>>(wf, wb, wt);
  prep_r<<<4096,256,0,stream>>>(rf, rb, rp);
  // layer 0
  proj_gemm<<<dim3(256,8,2),256,0,stream>>>(xb, xb, wt, 0, bf, bb, xz);
  rec_lstm<<<32,256,0,stream>>>(xz, rp, h, flags, 0);
  // layer 1 (input = layer-0 h series; residual handled in combine)
  proj_gemm<<<dim3(256,8,2),256,0,stream>>>(h, h + S, wt, 1, bf, bb, xz);
  rec_lstm<<<32,256,0,stream>>>(xz, rp, h + 2*S, flags + FL_PER_LAYER, 1);
  // merge: 0.5*((h1f+h0f)+(h1b+h0b))
  combine<<<8192,256,0,stream>>>(h, (float*)d_out);
}

// Round 14
// 1851.846 us; speedup vs baseline: 1.6908x; 1.6908x over previous
//
#include <hip/hip_runtime.h>

typedef unsigned short ushort_t;
typedef __attribute__((ext_vector_type(8))) short v8s;
typedef __attribute__((ext_vector_type(4))) float v4f;
typedef __attribute__((ext_vector_type(4))) unsigned int v4u;
typedef __attribute__((ext_vector_type(4))) unsigned short v4h;

#define DEV __device__ __forceinline__

#define BB 128
#define TT 256
#define DD 256
#define UU 256
#define NG 1024
#define TB 32768  // T*B

#define L2E  1.4426950408889634f
#define L2E2 2.8853901617779268f

DEV ushort_t f2bf(float f){
  unsigned u = __builtin_bit_cast(unsigned, f);
  u = u + 0x7FFFu + ((u>>16)&1u);
  return (ushort_t)(u>>16);
}
DEV float bf2f(ushort_t h){
  unsigned u = ((unsigned)h)<<16;
  return __builtin_bit_cast(float, u);
}
// ---- L3-coherent exchange ops (proven R10 protocol class: sc0 sc1 everywhere) ----
DEV void store_short_wt(ushort_t* p, ushort_t v){
  asm volatile("global_store_short %0, %1, off sc0 sc1" :: "v"(p), "v"((unsigned)v) : "memory");
}
DEV void st_tag(unsigned* p, unsigned v){
  asm volatile("global_store_dword %0, %1, off sc0 sc1" :: "v"(p), "v"(v) : "memory");
}
DEV v4u ld4_tag(const unsigned* p){
  v4u r;
  asm volatile("global_load_dwordx4 %0, %1, off sc0 sc1" : "=v"(r) : "v"(p) : "memory");
  return r;
}

// ---- prep: x (B,T,D) fp32 -> xb (T,B,D) bf16 ----
__global__ void prep_x(const float* __restrict__ x, ushort_t* __restrict__ xb){
  int tid = blockIdx.x*256 + threadIdx.x;
  int idx = tid*4;
  if (idx >= BB*TT*DD) return;
  int d0 = idx & 255, t = (idx>>8)&255, b = idx>>16;
  const float* s = x + ((size_t)(b*256+t))*256 + d0;
  ushort_t* o = xb + ((size_t)(t*128+b))*256 + d0;
  v4f v = *(const v4f*)s;
  o[0]=f2bf(v[0]); o[1]=f2bf(v[1]); o[2]=f2bf(v[2]); o[3]=f2bf(v[3]);
}

// ---- prep: W (L,K=256,N=1024) fp32 -> wt [d][L][n][k] bf16, pre-scaled by log2e ----
__global__ void prep_w(const float* __restrict__ wf, const float* __restrict__ wb,
                       ushort_t* __restrict__ wt){
  int tid = blockIdx.x*256 + threadIdx.x;           // 1,048,576 total
  int n = tid & 1023, k = (tid>>10)&255, L = (tid>>18)&1, d = (tid>>19)&1;
  const float* src = (d ? wb : wf) + (size_t)L*262144 + (size_t)k*1024 + n;
  float sc = ((n>>8)==2) ? L2E2 : L2E;
  wt[(size_t)((d*2+L)*1024 + n)*256 + k] = f2bf(*src * sc);
}

// ---- prep: R (L,256,1024) fp32 -> rp packed in MFMA B-fragment order, pre-scaled ----
__global__ void prep_r(const float* __restrict__ rf, const float* __restrict__ rb,
                       ushort_t* __restrict__ rp){
  int tid = blockIdx.x*256 + threadIdx.x;           // 1,048,576 total
  int gcol = tid & 1023, k = (tid>>10)&255, L = (tid>>18)&1, d = (tid>>19)&1;
  const float* src = (d ? rb : rf) + (size_t)L*262144 + (size_t)k*1024 + gcol;
  float sc = ((gcol>>8)==2) ? L2E2 : L2E;
  int g = gcol>>8, rem = gcol&255, slot = rem>>4, lo = rem&15;
  int ks = k>>5, hi = (k>>3)&3, j = k&7;
  int l = hi*16+lo, frag = ks*4+g;
  rp[(size_t)((d*2+L)*16 + slot)*16384 + (size_t)frag*512 + l*8 + j] = f2bf(*src * sc);
}

// ---- projection GEMM: xz[d][t*128+b][gc] = A @ W^T + bias*sc ----
// TAGGED: A is u32 (bf16<<16 | tag) -> repack pairs while staging.
template<bool TAGGED>
__global__ __launch_bounds__(256) void proj_gemm(
    const void* __restrict__ A_fw, const void* __restrict__ A_bw,
    const ushort_t* __restrict__ wt, int layer,
    const float* __restrict__ bias_fw, const float* __restrict__ bias_bw,
    ushort_t* __restrict__ xz)
{
  int d = blockIdx.z;
  const void* Asel = d ? A_bw : A_fw;
  const ushort_t* W = wt + (size_t)(d*2+layer)*262144;
  const float* bias = (d ? bias_bw : bias_fw) + layer*1024;
  ushort_t* out = xz + (size_t)d*TB*NG;
  int m0 = blockIdx.x*128, n0 = blockIdx.y*128;
  __shared__ ushort_t As[128*32];
  __shared__ ushort_t Bs[128*32];
  int tid = threadIdx.x;
  int w = tid>>6, l = tid&63, lo = l&15, hi = l>>4;
  int wm = w>>1, wn = w&1;
  v4f acc[4][4];
  #pragma unroll
  for (int i=0;i<4;++i)
    #pragma unroll
    for (int j=0;j<4;++j) acc[i][j] = (v4f){0.f,0.f,0.f,0.f};
  for (int kt=0; kt<8; ++kt){
    __syncthreads();
    #pragma unroll
    for (int p=0;p<2;++p){
      int c = tid + p*256;
      int row = c>>2, c4 = c&3;
      if constexpr (TAGGED){
        const unsigned* A = (const unsigned*)Asel + (size_t)(m0+row)*256 + kt*32 + c4*8;
        v4u t0 = *(const v4u*)A;
        v4u t1 = *(const v4u*)(A+4);
        v4u pk;
        pk[0] = (t0[0]>>16) | (t0[1] & 0xFFFF0000u);
        pk[1] = (t0[2]>>16) | (t0[3] & 0xFFFF0000u);
        pk[2] = (t1[0]>>16) | (t1[1] & 0xFFFF0000u);
        pk[3] = (t1[2]>>16) | (t1[3] & 0xFFFF0000u);
        *(v4u*)(As + (size_t)c*8) = pk;
      } else {
        const ushort_t* A = (const ushort_t*)Asel;
        *(v4u*)(As + (size_t)c*8) = *(const v4u*)(A + (size_t)(m0+row)*256 + kt*32 + c4*8);
      }
      *(v4u*)(Bs + (size_t)c*8) = *(const v4u*)(W + (size_t)(n0+row)*256 + kt*32 + c4*8);
    }
    __syncthreads();
    v8s af[4], bfv[4];
    #pragma unroll
    for (int mt=0;mt<4;++mt) af[mt] = *(const v8s*)(As + (size_t)(wm*64+mt*16+lo)*32 + hi*8);
    #pragma unroll
    for (int nt=0;nt<4;++nt) bfv[nt] = *(const v8s*)(Bs + (size_t)(wn*64+nt*16+lo)*32 + hi*8);
    #pragma unroll
    for (int mt=0;mt<4;++mt)
      #pragma unroll
      for (int nt=0;nt<4;++nt)
        acc[mt][nt] = __builtin_amdgcn_mfma_f32_16x16x32_bf16(af[mt], bfv[nt], acc[mt][nt], 0,0,0);
  }
  #pragma unroll
  for (int nt=0;nt<4;++nt){
    int col = n0 + wn*64 + nt*16 + lo;
    float bv = bias[col] * (((col>>8)==2) ? L2E2 : L2E);
    #pragma unroll
    for (int mt=0;mt<4;++mt){
      int row0 = m0 + wm*64 + mt*16 + hi*4;
      #pragma unroll
      for (int r=0;r<4;++r)
        out[(size_t)(row0+r)*NG + col] = f2bf(acc[mt][nt][r] + bv);
    }
  }
}

// ---- persistent LSTM recurrence, TAGGED exchange (no flags, no drains) ----
// 64 blocks x 256 thr (1 wave/SIMD). g = bid&15 (d=g>>3, bg=g&7), cw = bid>>4.
// Producer stores each h element as u32 (bf16<<16 | tag), tag = layer*256+s+1,
// sc0 sc1 (L3-coherent). Consumer polls the exact words it needs until all 64
// carry tag layer*256+s, then repacks to bf16 A-fragments. The store IS the
// publication: no vmcnt drain, no separate flag round-trip. Spin bounded.
__global__ __launch_bounds__(256,1) void rec_tag(
    const ushort_t* __restrict__ xz, const ushort_t* __restrict__ rp,
    unsigned* __restrict__ htb, int layer)
{
  int bid = blockIdx.x;
  int g = bid & 15, cw = bid >> 4;
  int d = g >> 3, bg = g & 7;
  int rev = d;
  int tid = threadIdx.x, w = tid>>6, l = tid&63, lo = l&15, hi = l>>4;
  int b0 = bg*16;
  int U0 = cw*64 + w*16;
  int slot = cw*4 + w;
  const ushort_t* xzd = xz + (size_t)d*TB*NG;
  unsigned* ht = htb + (size_t)(layer*2 + d)*TB*UU;
  unsigned base = (unsigned)layer*256u;

  v8s bfr[8][4];
  {
    const ushort_t* rpp = rp + (size_t)((d*2+layer)*16 + slot)*16384 + l*8;
    #pragma unroll
    for (int f=0;f<32;++f)
      ((v8s*)bfr)[f] = *(const v8s*)(rpp + (size_t)f*512);
  }
  float c[4] = {0.f,0.f,0.f,0.f};

  for (int s=0;s<256;++s){
    int t = rev ? 255-s : s;
    // xz prefetch (read-only stream from prior dispatch; plain cached loads)
    float xzv[4][4];
    #pragma unroll
    for (int gg=0;gg<4;++gg)
      #pragma unroll
      for (int r=0;r<4;++r)
        xzv[gg][r] = bf2f(xzd[(size_t)(t*128 + b0 + hi*4 + r)*NG + gg*256 + U0 + lo]);
    v4f acc[4];
    #pragma unroll
    for (int gg=0;gg<4;++gg) acc[gg] = (v4f){0.f,0.f,0.f,0.f};
    if (s>0){
      int tp = rev ? t+1 : t-1;
      const unsigned* hrow = ht + (size_t)(tp*128 + b0 + lo)*UU;
      unsigned want = base + (unsigned)s;
      v4u q[16];
      int spin = 0; bool ok;
      do {
        #pragma unroll
        for (int ks=0;ks<8;++ks){
          q[2*ks]   = ld4_tag(hrow + ks*32 + hi*8);
          q[2*ks+1] = ld4_tag(hrow + ks*32 + hi*8 + 4);
        }
        asm volatile("s_waitcnt vmcnt(0)" ::: "memory");
        __builtin_amdgcn_sched_barrier(0);   // rule-18: nothing hoists past the wait
        unsigned badv = 0u;
        #pragma unroll
        for (int i=0;i<16;++i)
          #pragma unroll
          for (int j=0;j<4;++j)
            badv |= (q[i][j] ^ want);
        ok = __all((badv & 0xFFFFu) == 0u);
      } while (!ok && ++spin < 50000);   // failsafe: wrong answer beats hang
      v8s a[8];
      #pragma unroll
      for (int ks=0;ks<8;++ks){
        v4u q0 = q[2*ks], q1 = q[2*ks+1], tm;
        tm[0] = (q0[0]>>16) | (q0[1] & 0xFFFF0000u);
        tm[1] = (q0[2]>>16) | (q0[3] & 0xFFFF0000u);
        tm[2] = (q1[0]>>16) | (q1[1] & 0xFFFF0000u);
        tm[3] = (q1[2]>>16) | (q1[3] & 0xFFFF0000u);
        a[ks] = __builtin_bit_cast(v8s, tm);
      }
      #pragma unroll
      for (int ks=0;ks<8;++ks)
        #pragma unroll
        for (int gg=0;gg<4;++gg)
          acc[gg] = __builtin_amdgcn_mfma_f32_16x16x32_bf16(a[ks], bfr[ks][gg], acc[gg], 0,0,0);
    }
    unsigned tagv = base + (unsigned)s + 1u;
    #pragma unroll
    for (int r=0;r<4;++r){
      float zi = acc[0][r] + xzv[0][r];   // pre-scaled by log2e
      float zf = acc[1][r] + xzv[1][r];
      float zg = acc[2][r] + xzv[2][r];   // pre-scaled by 2*log2e
      float zo = acc[3][r] + xzv[3][r];
      float ig = __builtin_amdgcn_rcpf(1.f + __builtin_amdgcn_exp2f(-zi));
      float fg = __builtin_amdgcn_rcpf(1.f + __builtin_amdgcn_exp2f(-zf));
      float og = __builtin_amdgcn_rcpf(1.f + __builtin_amdgcn_exp2f(-zo));
      float gt = 1.f - 2.f*__builtin_amdgcn_rcpf(1.f + __builtin_amdgcn_exp2f(zg));
      float cc = fg*c[r] + ig*gt;
      c[r] = cc;
      float th = 1.f - 2.f*__builtin_amdgcn_rcpf(1.f + __builtin_amdgcn_exp2f(L2E2*cc));
      unsigned wv = ((unsigned)f2bf(og*th) << 16) | tagv;
      st_tag(ht + (size_t)(t*128 + b0 + hi*4 + r)*UU + U0 + lo, wv);
    }
    // no drain, no flag: the tagged stores are the publication
  }
}

// ---- FALLBACK (ws too small): R10's proven flag-based rec ----
__global__ __launch_bounds__(256,1) void rec_flag(
    const ushort_t* __restrict__ xz, const ushort_t* __restrict__ rp,
    ushort_t* __restrict__ hbase, unsigned* __restrict__ flags, int layer)
{
  int bid = blockIdx.x;
  int g = bid & 15, cw = bid >> 4;
  int d = g >> 3, bg = g & 7;
  int rev = d;
  int tid = threadIdx.x, w = tid>>6, l = tid&63, lo = l&15, hi = l>>4;
  int b0 = bg*16;
  int U0 = cw*64 + w*16;
  int slot = cw*4 + w;
  const ushort_t* xzd = xz + (size_t)d*TB*NG;
  ushort_t* h = hbase + (size_t)d*TB*UU;
  unsigned* flg = flags + (size_t)g*4096;

  v8s bfr[8][4];
  {
    const ushort_t* rpp = rp + (size_t)((d*2+layer)*16 + slot)*16384 + l*8;
    #pragma unroll
    for (int f=0;f<32;++f)
      ((v8s*)bfr)[f] = *(const v8s*)(rpp + (size_t)f*512);
  }
  float c[4] = {0.f,0.f,0.f,0.f};

  for (int s=0;s<256;++s){
    int t = rev ? 255-s : s;
    float xzv[4][4];
    #pragma unroll
    for (int gg=0;gg<4;++gg)
      #pragma unroll
      for (int r=0;r<4;++r)
        xzv[gg][r] = bf2f(xzd[(size_t)(t*128 + b0 + hi*4 + r)*NG + gg*256 + U0 + lo]);
    v4f acc[4];
    #pragma unroll
    for (int gg=0;gg<4;++gg) acc[gg] = (v4f){0.f,0.f,0.f,0.f};
    if (s>0){
      unsigned v; int spin = 0;
      do {
        v = __hip_atomic_load(&flg[(s-1)*16 + (l&15)], __ATOMIC_RELAXED, __HIP_MEMORY_SCOPE_AGENT);
        if (++spin > 5000) break;
      } while (!__all(v != 0u));
      asm volatile("" ::: "memory");
      int tp = rev ? t+1 : t-1;
      v8s a[8];
      #pragma unroll
      for (int ks=0;ks<8;++ks)
        a[ks] = *(const v8s*)(h + (size_t)(tp*128 + b0 + lo)*UU + ks*32 + hi*8);
      #pragma unroll
      for (int ks=0;ks<8;++ks)
        #pragma unroll
        for (int gg=0;gg<4;++gg)
          acc[gg] = __builtin_amdgcn_mfma_f32_16x16x32_bf16(a[ks], bfr[ks][gg], acc[gg], 0,0,0);
    }
    #pragma unroll
    for (int r=0;r<4;++r){
      float zi = acc[0][r] + xzv[0][r];
      float zf = acc[1][r] + xzv[1][r];
      float zg = acc[2][r] + xzv[2][r];
      float zo = acc[3][r] + xzv[3][r];
      float ig = __builtin_amdgcn_rcpf(1.f + __builtin_amdgcn_exp2f(-zi));
      float fg = __builtin_amdgcn_rcpf(1.f + __builtin_amdgcn_exp2f(-zf));
      float og = __builtin_amdgcn_rcpf(1.f + __builtin_amdgcn_exp2f(-zo));
      float gt = 1.f - 2.f*__builtin_amdgcn_rcpf(1.f + __builtin_amdgcn_exp2f(zg));
      float cc = fg*c[r] + ig*gt;
      c[r] = cc;
      float th = 1.f - 2.f*__builtin_amdgcn_rcpf(1.f + __builtin_amdgcn_exp2f(L2E2*cc));
      store_short_wt(h + (size_t)(t*128 + b0 + hi*4 + r)*UU + U0 + lo, f2bf(og*th));
    }
    asm volatile("s_waitcnt vmcnt(0)" ::: "memory");
    if (l == 0)
      __hip_atomic_store(&flg[s*16 + slot], 1u, __ATOMIC_RELAXED, __HIP_MEMORY_SCOPE_AGENT);
  }
}

// ---- final combine (tagged): out fp32 = 0.5*(h1f + h0f + h1b + h0b) ----
__global__ void combine_tag(const unsigned* __restrict__ ht, float* __restrict__ out){
  int tid = blockIdx.x*256 + threadIdx.x;
  int idx = tid*4;
  if (idx >= BB*TT*UU) return;
  int u = idx&255, t = (idx>>8)&255, b = idx>>16;
  size_t o = (size_t)(t*128+b)*256 + u;
  const size_t S = (size_t)TB*UU;
  v4u a0 = *(const v4u*)(ht + 0*S + o);   // L0 fw
  v4u a1 = *(const v4u*)(ht + 1*S + o);   // L0 bw
  v4u a2 = *(const v4u*)(ht + 2*S + o);   // L1 fw
  v4u a3 = *(const v4u*)(ht + 3*S + o);   // L1 bw
  v4f res;
  #pragma unroll
  for (int k=0;k<4;++k)
    res[k] = 0.5f*(bf2f((ushort_t)(a0[k]>>16)) + bf2f((ushort_t)(a1[k]>>16))
                 + bf2f((ushort_t)(a2[k]>>16)) + bf2f((ushort_t)(a3[k]>>16)));
  *(v4f*)(out + ((size_t)(b*256+t))*256 + u) = res;
}

// ---- final combine (plain bf16 h; fallback path) ----
__global__ void combine_plain(const ushort_t* __restrict__ h, float* __restrict__ out){
  int tid = blockIdx.x*256 + threadIdx.x;
  int idx = tid*4;
  if (idx >= BB*TT*UU) return;
  int u = idx&255, t = (idx>>8)&255, b = idx>>16;
  size_t o = (size_t)(t*128+b)*256 + u;
  const size_t S = (size_t)TB*UU;
  v4h a0 = *(const v4h*)(h + 0*S + o);
  v4h a1 = *(const v4h*)(h + 1*S + o);
  v4h a2 = *(const v4h*)(h + 2*S + o);
  v4h a3 = *(const v4h*)(h + 3*S + o);
  v4f res;
  #pragma unroll
  for (int k=0;k<4;++k)
    res[k] = 0.5f*(bf2f(a0[k]) + bf2f(a1[k]) + bf2f(a2[k]) + bf2f(a3[k]));
  *(v4f*)(out + ((size_t)(b*256+t))*256 + u) = res;
}

extern "C" void kernel_launch(void* const* d_in, const int* in_sizes, int n_in,
                              void* d_out, int out_size, void* d_ws, size_t ws_size,
                              hipStream_t stream)
{
  const float* x  = (const float*)d_in[0];
  const float* wf = (const float*)d_in[1];
  const float* rf = (const float*)d_in[2];
  const float* bf = (const float*)d_in[3];
  const float* wb = (const float*)d_in[4];
  const float* rb = (const float*)d_in[5];
  const float* bb = (const float*)d_in[6];
  char* ws = (char*)d_ws;

  const size_t XB_OFF = 0;
  const size_t WT_OFF = XB_OFF + (size_t)TB*DD*2;            // 16,777,216
  const size_t RP_OFF = WT_OFF + (size_t)2*2*1024*256*2;     // +2,097,152
  const size_t XZ_OFF = RP_OFF + (size_t)2*2*256*1024*2;     // +2,097,152
  const size_t HT_OFF = XZ_OFF + (size_t)2*TB*NG*2;          // +134,217,728
  const size_t NEED_TAG = HT_OFF + (size_t)4*TB*UU*4;        // tagged u32 x 4 chains
  // fallback layout (R10): bf16 h + flags in the same region
  const size_t H_OFF  = HT_OFF;
  const size_t FL_OFF = H_OFF + (size_t)4*TB*UU*2;
  const size_t FL_PL  = 16*256*16;   // uints per layer

  ushort_t* xb = (ushort_t*)(ws + XB_OFF);
  ushort_t* wt = (ushort_t*)(ws + WT_OFF);
  ushort_t* rp = (ushort_t*)(ws + RP_OFF);
  ushort_t* xz = (ushort_t*)(ws + XZ_OFF);
  const size_t S = (size_t)TB*UU;

  prep_x<<<8192,256,0,stream>>>(x, xb);
  prep_w<<<4096,256,0,stream>>>(wf, wb, wt);
  prep_r<<<4096,256,0,stream>>>(rf, rb, rp);

  if (ws_size >= NEED_TAG){
    unsigned* ht = (unsigned*)(ws + HT_OFF);
    // layer 0
    proj_gemm<false><<<dim3(256,8,2),256,0,stream>>>(xb, xb, wt, 0, bf, bb, xz);
    rec_tag<<<64,256,0,stream>>>(xz, rp, ht, 0);
    // layer 1 (A = tagged L0 h chains)
    proj_gemm<true><<<dim3(256,8,2),256,0,stream>>>(ht + 0*S, ht + 1*S, wt, 1, bf, bb, xz);
    rec_tag<<<64,256,0,stream>>>(xz, rp, ht, 1);
    combine_tag<<<8192,256,0,stream>>>(ht, (float*)d_out);
  } else {
    ushort_t* h = (ushort_t*)(ws + H_OFF);
    unsigned* flags = (unsigned*)(ws + FL_OFF);
    hipMemsetAsync(flags, 0, 2*FL_PL*4, stream);
    proj_gemm<false><<<dim3(256,8,2),256,0,stream>>>(xb, xb, wt, 0, bf, bb, xz);
    rec_flag<<<64,256,0,stream>>>(xz, rp, h, flags, 0);
    proj_gemm<false><<<dim3(256,8,2),256,0,stream>>>(h, h + S, wt, 1, bf, bb, xz);
    rec_flag<<<64,256,0,stream>>>(xz, rp, h + 2*S, flags + FL_PL, 1);
    combine_plain<<<8192,256,0,stream>>>(h, (float*)d_out);
  }
}